// Round 2
// baseline (201.528 us; speedup 1.0000x reference)
//
#include <hip/hip_runtime.h>
#include <hip/hip_bf16.h>

typedef short bf16x8 __attribute__((ext_vector_type(8)));   // 8 bf16 (4 VGPRs)
typedef float f32x4  __attribute__((ext_vector_type(4)));
typedef unsigned short u16;

#define MFMA16(a, b, c) __builtin_amdgcn_mfma_f32_16x16x32_bf16((a), (b), (c), 0, 0, 0)

static __device__ __forceinline__ u16 f2b(float f) {
  __hip_bfloat16 h = __float2bfloat16(f);   // RNE
  return __builtin_bit_cast(u16, h);
}

// ---------------------------------------------------------------------------
// Prep 1: f32 -> bf16 transpose  dst[C][R] = (bf16)src[R][C]  (R,C mult of 32)
__global__ void transpose_f32_to_bf16(const float* __restrict__ src,
                                      u16* __restrict__ dst, int R, int C) {
  __shared__ u16 tile[32][33];
  const int tx = threadIdx.x;           // 0..31
  const int ty = threadIdx.y;           // 0..7
  const int c0 = blockIdx.x * 32;
  const int r0 = blockIdx.y * 32;
#pragma unroll
  for (int i = 0; i < 32; i += 8)
    tile[ty + i][tx] = f2b(src[(size_t)(r0 + ty + i) * C + (c0 + tx)]);
  __syncthreads();
#pragma unroll
  for (int i = 0; i < 32; i += 8)
    dst[(size_t)(c0 + ty + i) * R + (r0 + tx)] = tile[tx][ty + i];
}

// Prep 2: biasT[j][i] = pos_emb[(jx-ix+7)*15 + (jy-iy+7)]  (j = key, i = query)
__global__ void build_biasT(const float* __restrict__ pos, float* __restrict__ biasT) {
  int t = blockIdx.x * blockDim.x + threadIdx.x;  // 0..4095
  int j = t >> 6, i = t & 63;
  int ix = i >> 3, iy = i & 7;
  int jx = j >> 3, jy = j & 7;
  biasT[t] = pos[(jx - ix + 7) * 15 + (jy - iy + 7)];
}

// ---------------------------------------------------------------------------
// Fused window attention: 1 block = 1 window (64 tokens), 8 waves = 8 heads.
// Phases: stage X (f32->bf16) -> QKV (mfma) -> per-head attention
// (swapped-operand mfma, in-register softmax) -> projection (mfma) -> f32 store.
__global__ __launch_bounds__(512, 2)
void winattn_fused(const float* __restrict__ x,
                   const u16* __restrict__ wqkvT,   // [768][256] bf16
                   const u16* __restrict__ woutT,   // [256][256] bf16
                   const float* __restrict__ b_out, // [256] f32
                   const float* __restrict__ biasT, // [64][64] f32 (key-major)
                   float* __restrict__ out) {
  __shared__ u16  Xs[64][264];    // X tile (bf16); reused as attn-out (AO)
  __shared__ u16  Qs[64][264];    // Q[tok][inner]; head slice reused for P[tq][tk<32]
  __shared__ u16  Ks[64][264];    // K[tok][inner]; slice reused for P[tq][tk>=32]
  __shared__ u16  VTs[256][72];   // V^T[inner][tok]
  __shared__ float Bs[64][68];    // biasT staged (padded stride 68)

  const int tid  = threadIdx.x;
  const int lane = tid & 63;
  const int wave = tid >> 6;      // 0..7
  const int c    = lane & 15;     // mfma 16-group
  const int g    = lane >> 4;     // 0..3

  const int win = blockIdx.x;     // 0..2047
  const int img = win >> 8;       // b*l image
  const int wid = win & 255;
  const int py0 = (wid >> 4) << 3;
  const int px0 = (wid & 15) << 3;
  const size_t imgbase = (size_t)img * (128 * 128);

  const f32x4 fzero = {0.f, 0.f, 0.f, 0.f};

  // ---- P0: stage X window tile (f32 coalesced, bf16 into LDS) + bias table
#pragma unroll
  for (int it = 0; it < 8; ++it) {
    int chunk = tid + it * 512;           // 4096 chunks: 64 rows x 64 float4
    int row = chunk >> 6;
    int c4 = (chunk & 63) << 2;
    int py = py0 + (row >> 3), px = px0 + (row & 7);
    const float4 v = *reinterpret_cast<const float4*>(
        x + ((size_t)(imgbase + py * 128 + px)) * 256 + c4);
    ushort4 pk;
    pk.x = f2b(v.x); pk.y = f2b(v.y); pk.z = f2b(v.z); pk.w = f2b(v.w);
    *reinterpret_cast<ushort4*>(&Xs[row][c4]) = pk;
  }
#pragma unroll
  for (int it = 0; it < 8; ++it) {
    int idx = tid + it * 512;             // 0..4095
    Bs[idx >> 6][idx & 63] = biasT[idx];
  }
  __syncthreads();

  // ---- P1: QKV = X @ Wqkv. 48 n-tiles; wave owns 6; B-frags reused over 4 m-tiles.
#pragma unroll 1
  for (int j = 0; j < 6; ++j) {
    const int nt = wave * 6 + j;          // qkv col tile 0..47
    const u16* wrow = wqkvT + (size_t)(nt * 16 + c) * 256;
    bf16x8 bfr[8];
#pragma unroll
    for (int k8 = 0; k8 < 8; ++k8)
      bfr[k8] = *reinterpret_cast<const bf16x8*>(&wrow[k8 * 32 + g * 8]);
    f32x4 acc[4];
#pragma unroll
    for (int mt = 0; mt < 4; ++mt) acc[mt] = fzero;
#pragma unroll
    for (int k8 = 0; k8 < 8; ++k8) {
#pragma unroll
      for (int mt = 0; mt < 4; ++mt) {
        bf16x8 a = *reinterpret_cast<const bf16x8*>(&Xs[mt * 16 + c][k8 * 32 + g * 8]);
        acc[mt] = MFMA16(a, bfr[k8], acc[mt]);
      }
    }
    // D layout: row = 4g+r (+16mt), col = c (+16nt)
#pragma unroll
    for (int mt = 0; mt < 4; ++mt) {
      if (nt < 16) {                       // Q
        const int colb = nt * 16 + c;
#pragma unroll
        for (int r = 0; r < 4; ++r) Qs[mt * 16 + g * 4 + r][colb] = f2b(acc[mt][r]);
      } else if (nt < 32) {                // K
        const int colb = (nt - 16) * 16 + c;
#pragma unroll
        for (int r = 0; r < 4; ++r) Ks[mt * 16 + g * 4 + r][colb] = f2b(acc[mt][r]);
      } else {                             // V -> V^T (4 contiguous tokens packed)
        ushort4 pk;
        pk.x = f2b(acc[mt][0]); pk.y = f2b(acc[mt][1]);
        pk.z = f2b(acc[mt][2]); pk.w = f2b(acc[mt][3]);
        *reinterpret_cast<ushort4*>(&VTs[(nt - 32) * 16 + c][mt * 16 + g * 4]) = pk;
      }
    }
  }
  __syncthreads();

  // ---- P2: attention, head h = wave. S^T = mfma(K, Q): lane holds
  // (tk = 16*tkt + 4g + r, tq = 16*tqt + c); softmax reduces over tk (g + regs).
  {
    const int hc = wave * 32;
    f32x4 st[4][4];
#pragma unroll
    for (int tkt = 0; tkt < 4; ++tkt) {
      bf16x8 a = *reinterpret_cast<const bf16x8*>(&Ks[tkt * 16 + c][hc + g * 8]);
#pragma unroll
      for (int tqt = 0; tqt < 4; ++tqt) {
        bf16x8 b = *reinterpret_cast<const bf16x8*>(&Qs[tqt * 16 + c][hc + g * 8]);
        st[tkt][tqt] = MFMA16(a, b, fzero);
      }
    }
    const float scale = 0.17677669529663689f;   // 32^-0.5
    float rs[4];
#pragma unroll
    for (int tqt = 0; tqt < 4; ++tqt) {
      float mx = -3.0e38f;
#pragma unroll
      for (int tkt = 0; tkt < 4; ++tkt)
#pragma unroll
        for (int r = 0; r < 4; ++r) {
          float z = st[tkt][tqt][r] * scale + Bs[tkt * 16 + g * 4 + r][tqt * 16 + c];
          st[tkt][tqt][r] = z;
          mx = fmaxf(mx, z);
        }
      mx = fmaxf(mx, __shfl_xor(mx, 16));
      mx = fmaxf(mx, __shfl_xor(mx, 32));
      float sum = 0.f;
#pragma unroll
      for (int tkt = 0; tkt < 4; ++tkt)
#pragma unroll
        for (int r = 0; r < 4; ++r) {
          float p = __expf(st[tkt][tqt][r] - mx);
          st[tkt][tqt][r] = p;
          sum += p;
        }
      sum += __shfl_xor(sum, 16);
      sum += __shfl_xor(sum, 32);
      rs[tqt] = 1.0f / sum;                 // normalize after PV (linear)
    }
    // P[tq][tk] (unnormalized bf16) into dead Q/K head slices: tk<32 -> Qs, else Ks
#pragma unroll
    for (int tkt = 0; tkt < 4; ++tkt)
#pragma unroll
      for (int tqt = 0; tqt < 4; ++tqt) {
        ushort4 pk;
        pk.x = f2b(st[tkt][tqt][0]); pk.y = f2b(st[tkt][tqt][1]);
        pk.z = f2b(st[tkt][tqt][2]); pk.w = f2b(st[tkt][tqt][3]);
        const int row = tqt * 16 + c;
        if (tkt < 2)
          *reinterpret_cast<ushort4*>(&Qs[row][hc + tkt * 16 + g * 4]) = pk;
        else
          *reinterpret_cast<ushort4*>(&Ks[row][hc + (tkt - 2) * 16 + g * 4]) = pk;
      }
    // O^T = mfma(V^T, P^T): out(d = 16mt+4g+r, tq = 16nt+c); rs[nt] lane-local.
#pragma unroll
    for (int mt = 0; mt < 2; ++mt)
#pragma unroll
      for (int nt = 0; nt < 4; ++nt) {
        f32x4 acc = fzero;
        {
          bf16x8 a = *reinterpret_cast<const bf16x8*>(&VTs[hc + mt * 16 + c][g * 8]);
          bf16x8 b = *reinterpret_cast<const bf16x8*>(&Qs[nt * 16 + c][hc + g * 8]);
          acc = MFMA16(a, b, acc);
        }
        {
          bf16x8 a = *reinterpret_cast<const bf16x8*>(&VTs[hc + mt * 16 + c][32 + g * 8]);
          bf16x8 b = *reinterpret_cast<const bf16x8*>(&Ks[nt * 16 + c][hc + g * 8]);
          acc = MFMA16(a, b, acc);
        }
        ushort4 pk;
        pk.x = f2b(acc[0] * rs[nt]); pk.y = f2b(acc[1] * rs[nt]);
        pk.z = f2b(acc[2] * rs[nt]); pk.w = f2b(acc[3] * rs[nt]);
        // AO (=Xs): AO[tq][hc + 16mt + 4g + r], 4 contiguous -> packed
        *reinterpret_cast<ushort4*>(&Xs[nt * 16 + c][hc + mt * 16 + g * 4]) = pk;
      }
  }
  __syncthreads();

  // ---- P3: Y = AO @ Wout + b_out, stored straight to global f32.
#pragma unroll 1
  for (int j = 0; j < 2; ++j) {
    const int nt = wave * 2 + j;
    const u16* wrow = woutT + (size_t)(nt * 16 + c) * 256;
    bf16x8 bfr[8];
#pragma unroll
    for (int k8 = 0; k8 < 8; ++k8)
      bfr[k8] = *reinterpret_cast<const bf16x8*>(&wrow[k8 * 32 + g * 8]);
    f32x4 acc[4];
#pragma unroll
    for (int mt = 0; mt < 4; ++mt) acc[mt] = fzero;
#pragma unroll
    for (int k8 = 0; k8 < 8; ++k8)
#pragma unroll
      for (int mt = 0; mt < 4; ++mt) {
        bf16x8 a = *reinterpret_cast<const bf16x8*>(&Xs[mt * 16 + c][k8 * 32 + g * 8]);
        acc[mt] = MFMA16(a, bfr[k8], acc[mt]);
      }
    const float bo = b_out[nt * 16 + c];
    // D: row (token) = mt*16 + 4g + r, col = nt*16 + c. 16-lane x 64B segments.
#pragma unroll
    for (int mt = 0; mt < 4; ++mt)
#pragma unroll
      for (int r = 0; r < 4; ++r) {
        const int row = mt * 16 + g * 4 + r;
        const int py = py0 + (row >> 3), px = px0 + (row & 7);
        out[((size_t)(imgbase + py * 128 + px)) * 256 + nt * 16 + c] = acc[mt][r] + bo;
      }
  }
}

// ---------------------------------------------------------------------------
extern "C" void kernel_launch(void* const* d_in, const int* in_sizes, int n_in,
                              void* d_out, int out_size, void* d_ws, size_t ws_size,
                              hipStream_t stream) {
  const float* x    = (const float*)d_in[0];   // [2,4,128,128,256] f32
  const float* wqkv = (const float*)d_in[1];   // [256,768] f32
  const float* wout = (const float*)d_in[2];   // [256,256] f32
  const float* bout = (const float*)d_in[3];   // [256] f32
  const float* pos  = (const float*)d_in[4];   // [15,15] f32
  float* out = (float*)d_out;

  u16*  wqkvT = (u16*)d_ws;                    // 768*256 bf16 = 384 KiB
  u16*  woutT = wqkvT + 768 * 256;             // 256*256 bf16 = 128 KiB
  float* biasT = (float*)(woutT + 256 * 256);  // 64*64 f32 = 16 KiB

  transpose_f32_to_bf16<<<dim3(768 / 32, 256 / 32), dim3(32, 8), 0, stream>>>(
      wqkv, wqkvT, 256, 768);
  transpose_f32_to_bf16<<<dim3(256 / 32, 256 / 32), dim3(32, 8), 0, stream>>>(
      wout, woutT, 256, 256);
  build_biasT<<<16, 256, 0, stream>>>(pos, biasT);

  winattn_fused<<<2048, 512, 0, stream>>>(x, wqkvT, woutT, bout, biasT, out);
}